// Round 6
// baseline (149.724 us; speedup 1.0000x reference)
//
#include <hip/hip_runtime.h>
#include <hip/hip_fp16.h>

// ---------------------------------------------------------------------------
// DotProductAttention: O = softmax((Q K^T / sqrt(128)) * p_q * p_k^T) V
// B=16, S=2048, D=128, fp32 in/out.
// Fold scale*p_q*log2(e) into Q, p_k into K (exact rank-1 folds), cast fp16,
// flash-attention with swapped-QK^T 32x32x16 MFMAs in log2-softmax domain.
// Round 6: same split-K design as round 5 (2 blocks/CU = 4 waves/SIMD), with
// the LDS overflow fixed: ml exchange array needs 2 KB for 8 waves ->
// ldsraw enlarged 66560 -> 67584 B. (Round 5's ml overran the allocation,
// corrupting waves 4-7's merge weights.)
// ---------------------------------------------------------------------------

typedef _Float16 f16x8 __attribute__((ext_vector_type(8)));
typedef float f32x16 __attribute__((ext_vector_type(16)));
typedef unsigned int u32x4 __attribute__((ext_vector_type(4)));

#define S_LEN 2048
#define DD 128
#define TILE_BYTES 16384   // 64 keys x 128 d x 2B (one image tile)
#define NT 32              // kv tiles of 64 keys per batch
#define NTH 16             // tiles per key-half (split-K factor 2)
#define PART_ROWS 32768    // 16 batches * 2048 q-rows
#define PART_STRIDE 4194304  // PART_ROWS * 128 elems per kh slab

#define EXP2(x) __builtin_amdgcn_exp2f(x)   // raw v_exp_f32 (2^x)

__device__ __forceinline__ unsigned int pk2(float a, float b) {
  __half2 h = __float22half2_rn(make_float2(a, b));
  return __builtin_bit_cast(unsigned int, h);
}

__device__ __forceinline__ void st8(void* dst, const float v[8]) {
  u32x4 u;
  u[0] = pk2(v[0], v[1]);
  u[1] = pk2(v[2], v[3]);
  u[2] = pk2(v[4], v[5]);
  u[3] = pk2(v[6], v[7]);
  *(u32x4*)dst = u;
}

__device__ __forceinline__ void gld16(const void* g, void* l) {
  __builtin_amdgcn_global_load_lds(
      (const __attribute__((address_space(1))) unsigned int*)g,
      (__attribute__((address_space(3))) unsigned int*)l, 16, 0, 0);
}

// --------------------------- pre-pass: Q --------------------------------
// Q' = fp16(Q * (log2e/sqrt(128)) * p_q[row]); row-major [B*S][128]
__global__ __launch_bounds__(256) void prep_q_k(const float* __restrict__ Q,
                                                const float* __restrict__ pq,
                                                char* __restrict__ qh) {
  size_t i = ((size_t)blockIdx.x * 256 + threadIdx.x) * 8;
  const float g = pq[i >> 7] * 0.12751743343158394f;  // (1/sqrt(128))*log2(e)
  float4 a = *(const float4*)(Q + i);
  float4 b = *(const float4*)(Q + i + 4);
  float v[8] = {a.x * g, a.y * g, a.z * g, a.w * g,
                b.x * g, b.y * g, b.z * g, b.w * g};
  st8(qh + i * 2, v);
}

// --------------------------- pre-pass: K,V images ------------------------
// K image tile (64x128): byte(key,d) = key*256 + ((2d) ^ ((key&7)<<4))
// V image tile:          byte(key,d) = d*128 + ((2key) ^ ((d&7)<<4))
__global__ __launch_bounds__(256) void prep_kv(
    const float* __restrict__ K, const float* __restrict__ V,
    const float* __restrict__ pk, char* __restrict__ kimg,
    char* __restrict__ vimg) {
  __shared__ float vt[64 * 132];
  const int t = threadIdx.x;
  const int bid = blockIdx.x;
  const int bq = bid & 15;
  const int kt = bid >> 4;
  const size_t rowbase = (size_t)bq * S_LEN + kt * 64;

  // stage V tile (fp32) into padded LDS for the transpose
#pragma unroll
  for (int cc = 0; cc < 8; ++cc) {
    const int f = cc * 256 + t;
    const int row = f >> 5;
    const int col = (f & 31) * 4;
    *(float4*)(vt + row * 132 + col) = *(const float4*)(V + (rowbase + row) * DD + col);
  }

  // K image: pure global->global, fold p_k
  char* kdst = kimg + (size_t)(bq * NT + kt) * TILE_BYTES;
#pragma unroll
  for (int cc = 0; cc < 4; ++cc) {
    const int p0 = (cc * 256 + t) * 16;
    const int key = p0 >> 8;
    const int d0 = ((p0 & 255) ^ ((key & 7) << 4)) >> 1;
    const float g = pk[rowbase + key];
    const float* src = K + (rowbase + key) * DD + d0;
    float4 a = *(const float4*)(src);
    float4 b = *(const float4*)(src + 4);
    float v[8] = {a.x * g, a.y * g, a.z * g, a.w * g,
                  b.x * g, b.y * g, b.z * g, b.w * g};
    st8(kdst + p0, v);
  }

  __syncthreads();

  // V image from LDS transpose
  char* vdst = vimg + (size_t)(bq * NT + kt) * TILE_BYTES;
#pragma unroll
  for (int cc = 0; cc < 4; ++cc) {
    const int p0 = (cc * 256 + t) * 16;
    const int dcol = p0 >> 7;
    const int key0 = ((p0 & 127) ^ ((dcol & 7) << 4)) >> 1;
    float v[8];
#pragma unroll
    for (int j = 0; j < 8; ++j) v[j] = vt[(key0 + j) * 132 + dcol];
    st8(vdst + p0, v);
  }
}

// --------------------------- main attention ------------------------------
// 512 threads = 8 waves: wid = qs*2 + ks; qs in [0,4) picks a 32-q subtile,
// ks in {0,1} picks the key-half of each 64-key tile. Block covers key range
// [kh*1024, kh*1024+1024). Emits fp16 partial means + (m,l) per q-row.
__global__ __launch_bounds__(512, 4) void attn_main(const char* __restrict__ qh,
                                                    const char* __restrict__ kimg,
                                                    const char* __restrict__ vimg,
                                                    _Float16* __restrict__ part,
                                                    float2* __restrict__ mlws) {
  __shared__ float4 ldsraw[4224];  // 67584 B: 2x32KB stage dbuf (+64KB T alias) + 2KB ml
  char* lds = (char*)ldsraw;
  const int tid = threadIdx.x;
  const int wid = tid >> 6;
  const int qs = wid >> 1;   // q subtile 0..3
  const int ks = wid & 1;    // key half of tile 0..1
  const int lane = tid & 63;
  const int c = lane & 31;
  const int h = lane >> 5;
  const int swz = (c & 7) << 4;
  const int bid = blockIdx.x;
  const int bq = 2 * (bid & 7) + ((bid >> 3) & 1);  // batch pinned to XCD
  const int qt = (bid >> 4) & 15;                   // q-tile (128 rows)
  const int kh = bid >> 8;                          // key-half 0..1
  const int q0 = qt * 128 + qs * 32;

  // Q fragments (B-operand of swapped QK^T): lane c = q row, 8 d's per kc
  f16x8 qf[8];
  const char* qrow = qh + (size_t)(bq * S_LEN + q0 + c) * (DD * 2);
#pragma unroll
  for (int kc = 0; kc < 8; ++kc) qf[kc] = *(const f16x8*)(qrow + kc * 32 + h * 16);

  f32x16 acc[4];
#pragma unroll
  for (int d = 0; d < 4; ++d) {
#pragma unroll
    for (int r = 0; r < 16; ++r) acc[d][r] = 0.f;
  }
  float m_run = -1.0e30f, l_run = 0.f;

  const char* kb = kimg + (size_t)(bq * NT + kh * NTH) * TILE_BYTES;
  const char* vb = vimg + (size_t)(bq * NT + kh * NTH) * TILE_BYTES;

  // prologue: stage tile 0 into buffer 0 (linear copy of pre-swizzled image)
#pragma unroll
  for (int j = 0; j < 2; ++j) {
    gld16(kb + j * 8192 + tid * 16, lds + j * 8192 + tid * 16);
    gld16(vb + j * 8192 + tid * 16, lds + TILE_BYTES + j * 8192 + tid * 16);
  }

  for (int kt = 0; kt < NTH; ++kt) {
    __syncthreads();  // drains staging vmcnt; frees other buffer
    const int cur = (kt & 1) << 15;
    if (kt + 1 < NTH) {
      const int nxt = ((kt + 1) & 1) << 15;
      const char* kn = kb + (size_t)(kt + 1) * TILE_BYTES;
      const char* vn = vb + (size_t)(kt + 1) * TILE_BYTES;
#pragma unroll
      for (int j = 0; j < 2; ++j) {
        gld16(kn + j * 8192 + tid * 16, lds + nxt + j * 8192 + tid * 16);
        gld16(vn + j * 8192 + tid * 16, lds + nxt + TILE_BYTES + j * 8192 + tid * 16);
      }
    }
    const char* kl = lds + cur;
    const char* vl = lds + cur + TILE_BYTES;

    // S^T = K' Q'^T over this wave's 32-key half
    f32x16 s;
#pragma unroll
    for (int r = 0; r < 16; ++r) s[r] = 0.f;
    __builtin_amdgcn_s_setprio(1);
#pragma unroll
    for (int kc = 0; kc < 8; ++kc) {
      f16x8 kf = *(const f16x8*)(kl + (ks * 32 + c) * 256 + ((kc * 32 + h * 16) ^ swz));
      s = __builtin_amdgcn_mfma_f32_32x32x16_f16(kf, qf[kc], s, 0, 0, 0);
    }
    __builtin_amdgcn_s_setprio(0);

    // lane-local online softmax (log2 domain; row q = c); tree reductions
    float m0 = fmaxf(s[0], s[1]), m1 = fmaxf(s[2], s[3]);
    float m2 = fmaxf(s[4], s[5]), m3 = fmaxf(s[6], s[7]);
    float m4 = fmaxf(s[8], s[9]), m5 = fmaxf(s[10], s[11]);
    float m6 = fmaxf(s[12], s[13]), m7 = fmaxf(s[14], s[15]);
    m0 = fmaxf(m0, m1); m2 = fmaxf(m2, m3); m4 = fmaxf(m4, m5); m6 = fmaxf(m6, m7);
    float cm = fmaxf(fmaxf(m0, m2), fmaxf(m4, m6));
    cm = fmaxf(cm, __shfl_xor(cm, 32));
    if (__any(cm > m_run + 11.0f)) {  // defer-max: rescale only on real growth
      const float mn = fmaxf(m_run, cm);
      const float al = EXP2(m_run - mn);
      m_run = mn;
      l_run *= al;
#pragma unroll
      for (int d = 0; d < 4; ++d) {
#pragma unroll
        for (int r = 0; r < 16; ++r) acc[d][r] *= al;
      }
    }
    float ps0 = 0.f, ps1 = 0.f;
#pragma unroll
    for (int r = 0; r < 8; ++r) {
      s[r] = EXP2(s[r] - m_run);         ps0 += s[r];
      s[r + 8] = EXP2(s[r + 8] - m_run); ps1 += s[r + 8];
    }
    l_run += ps0 + ps1;

    // PV: O^T += V^T P^T over the wave's two local 16-key chunks
#pragma unroll
    for (int kc = 0; kc < 2; ++kc) {
      const int A = kc * 8;
      const int Bb = A + 4;
      unsigned pA0 = pk2(s[A + 0], s[A + 1]);
      unsigned pA1 = pk2(s[A + 2], s[A + 3]);
      unsigned pB0 = pk2(s[Bb + 0], s[Bb + 1]);
      unsigned pB1 = pk2(s[Bb + 2], s[Bb + 3]);
      unsigned own0 = h ? pB0 : pA0;
      unsigned own1 = h ? pB1 : pA1;
      unsigned snd0 = h ? pA0 : pB0;
      unsigned snd1 = h ? pA1 : pB1;
      unsigned rcv0 = __shfl_xor(snd0, 32);
      unsigned rcv1 = __shfl_xor(snd1, 32);
      u32x4 pw;
      pw[0] = h ? rcv0 : own0;  // elems 0,1 (source half h=0)
      pw[1] = h ? rcv1 : own1;  // elems 2,3
      pw[2] = h ? own0 : rcv0;  // elems 4,5 (source half h=1)
      pw[3] = h ? own1 : rcv1;  // elems 6,7
      f16x8 pf = __builtin_bit_cast(f16x8, pw);
      const int kci = ks * 2 + kc;  // global 16-key chunk in tile
      __builtin_amdgcn_s_setprio(1);
#pragma unroll
      for (int d = 0; d < 4; ++d) {
        f16x8 vf = *(const f16x8*)(vl + (d * 32 + c) * 128 + ((kci * 32 + h * 16) ^ swz));
        acc[d] = __builtin_amdgcn_mfma_f32_32x32x16_f16(vf, pf, acc[d], 0, 0, 0);
      }
      __builtin_amdgcn_s_setprio(0);
    }
  }

  // ---- epilogue: merge the two ks partials, store fp16 partial mean ----
  l_run += __shfl_xor(l_run, 32);  // full half-range sum for row q=c

  __syncthreads();  // all waves done with stage buffers
  float2* ml = (float2*)(lds + 65536);
  if (h == 0) ml[wid * 32 + c] = make_float2(m_run, l_run);
  __syncthreads();
  const float2 po = ml[(wid ^ 1) * 32 + c];  // partner key-half (same qs)
  const float ms = fmaxf(m_run, po.x);
  const float lstar = l_run * EXP2(m_run - ms) + po.y * EXP2(po.x - ms);
  const float w = EXP2(m_run - ms) / lstar;   // -> T holds the block's partial MEAN

  char* T = lds;  // 128 q x 128 d fp32 (64KB), swizzled rows
  if (ks == 0) {
#pragma unroll
    for (int d = 0; d < 4; ++d) {
#pragma unroll
      for (int rr = 0; rr < 4; ++rr) {
        const int dd = d * 32 + rr * 8 + h * 4;
        float4 v4;
        v4.x = acc[d][rr * 4 + 0] * w;
        v4.y = acc[d][rr * 4 + 1] * w;
        v4.z = acc[d][rr * 4 + 2] * w;
        v4.w = acc[d][rr * 4 + 3] * w;
        *(float4*)(T + (qs * 32 + c) * 512 + ((dd * 4) ^ swz)) = v4;
      }
    }
  }
  __syncthreads();
  if (ks == 1) {
#pragma unroll
    for (int d = 0; d < 4; ++d) {
#pragma unroll
      for (int rr = 0; rr < 4; ++rr) {
        const int dd = d * 32 + rr * 8 + h * 4;
        float4* p = (float4*)(T + (qs * 32 + c) * 512 + ((dd * 4) ^ swz));
        float4 t = *p;
        t.x += acc[d][rr * 4 + 0] * w;
        t.y += acc[d][rr * 4 + 1] * w;
        t.z += acc[d][rr * 4 + 2] * w;
        t.w += acc[d][rr * 4 + 3] * w;
        *p = t;
      }
    }
  }
  __syncthreads();

  // fp16 partial mean -> part[kh][bq*2048 + qt*128 + row][d]
  const size_t prow = (size_t)bq * S_LEN + qt * 128;
  _Float16* pdst = part + (size_t)kh * PART_STRIDE + prow * 128;
#pragma unroll
  for (int p = 0; p < 4; ++p) {
    const int idx = p * 512 + tid;
    const int row = idx >> 4;
    const int d0 = (idx & 15) * 8;
    const int swzT = (row & 7) << 4;
    float4 A = *(const float4*)(T + row * 512 + ((d0 * 4) ^ swzT));
    float4 Bv = *(const float4*)(T + row * 512 + (((d0 * 4) + 16) ^ swzT));
    float v[8] = {A.x, A.y, A.z, A.w, Bv.x, Bv.y, Bv.z, Bv.w};
    st8((void*)(pdst + row * 128 + d0), v);
  }
  if (ks == 0 && h == 0)
    mlws[(size_t)kh * PART_ROWS + prow + qs * 32 + c] = make_float2(ms, lstar);
}

// --------------------------- split-K merge --------------------------------
// O[r][d] = (p0*l0*2^(m0-M) + p1*l1*2^(m1-M)) / (l0*2^(m0-M) + l1*2^(m1-M))
__global__ __launch_bounds__(256) void merge2(const _Float16* __restrict__ part,
                                              const float2* __restrict__ mlws,
                                              float* __restrict__ out) {
  const int t = blockIdx.x * 256 + threadIdx.x;
  const int d0 = (t & 15) * 8;
  const int r = t >> 4;  // global row = b*2048 + q
  const float2 a = mlws[r];
  const float2 b = mlws[PART_ROWS + r];
  const float M = fmaxf(a.x, b.x);
  const float wa = a.y * EXP2(a.x - M);
  const float wb = b.y * EXP2(b.x - M);
  const float inv = 1.f / (wa + wb);
  const float fa = wa * inv, fb = wb * inv;
  const f16x8 pa = *(const f16x8*)(part + (size_t)r * 128 + d0);
  const f16x8 pb = *(const f16x8*)(part + PART_STRIDE + (size_t)r * 128 + d0);
  float4 o0, o1;
  o0.x = fa * (float)pa[0] + fb * (float)pb[0];
  o0.y = fa * (float)pa[1] + fb * (float)pb[1];
  o0.z = fa * (float)pa[2] + fb * (float)pb[2];
  o0.w = fa * (float)pa[3] + fb * (float)pb[3];
  o1.x = fa * (float)pa[4] + fb * (float)pb[4];
  o1.y = fa * (float)pa[5] + fb * (float)pb[5];
  o1.z = fa * (float)pa[6] + fb * (float)pb[6];
  o1.w = fa * (float)pa[7] + fb * (float)pb[7];
  float* orow = out + (size_t)r * 128 + d0;
  *(float4*)orow = o0;
  *(float4*)(orow + 4) = o1;
}

// --------------------------- launcher ------------------------------------
extern "C" void kernel_launch(void* const* d_in, const int* in_sizes, int n_in,
                              void* d_out, int out_size, void* d_ws, size_t ws_size,
                              hipStream_t stream) {
  const float* Q = (const float*)d_in[0];
  const float* K = (const float*)d_in[1];
  const float* V = (const float*)d_in[2];
  const float* pq = (const float*)d_in[3];
  const float* pk = (const float*)d_in[4];
  float* out = (float*)d_out;
  char* ws = (char*)d_ws;
  char* qh = ws;                              // 8 MB fp16 scaled Q (log2e folded)
  char* kimg = ws + (8u << 20);               // 8 MB K image (gated, swizzled)
  char* vimg = ws + (16u << 20);              // 8 MB V image (transposed, swizzled)
  _Float16* part = (_Float16*)(ws + (24u << 20));  // 16 MB fp16 partial means (2 slabs)
  float2* mlws = (float2*)(ws + (42u << 20));      // 0.5 MB (m,l) per row per slab

  prep_q_k<<<2048, 256, 0, stream>>>(Q, pq, qh);
  prep_kv<<<512, 256, 0, stream>>>(K, V, pk, kimg, vimg);
  attn_main<<<512, 512, 0, stream>>>(qh, kimg, vimg, part, mlws);
  merge2<<<2048, 256, 0, stream>>>(part, mlws, out);
}

// Round 7
// 66.665 us; speedup vs baseline: 2.2459x; 2.2459x over previous
//
#include <hip/hip_runtime.h>
#include <hip/hip_fp16.h>

// ---------------------------------------------------------------------------
// DotProductAttention: O = softmax((Q K^T / sqrt(128)) * p_q * p_k^T) V
// B=16, S=2048, D=128, fp32 in/out.
// Fold scale*p_q*log2(e) into Q, p_k into K (exact rank-1 folds), cast fp16,
// flash-attention with swapped-QK^T 32x32x16 MFMAs in log2-softmax domain.
// Round 7: revert split-K (r6 spilled: launch_bounds(512,4) -> 64 VGPR cap).
// Back to r3 structure (grid 256, 8 waves, 2/SIMD) + T15 2-deep pipeline:
// QK(t+1) MFMAs issue BEFORE softmax(t) VALU, so the VALU runs in the MFMA
// shadow; K gets a 3-slot ring, V double-buffered; one barrier per iter.
// ---------------------------------------------------------------------------

typedef _Float16 f16x8 __attribute__((ext_vector_type(8)));
typedef float f32x16 __attribute__((ext_vector_type(16)));
typedef unsigned int u32x4 __attribute__((ext_vector_type(4)));

#define S_LEN 2048
#define DD 128
#define TILE_BYTES 16384   // 64 keys x 128 d x 2B (one image tile)
#define NT 32              // kv tiles of 64 keys per batch

#define EXP2(x) __builtin_amdgcn_exp2f(x)   // raw v_exp_f32 (2^x)

// LDS map (bytes): K ring slots 0/16384/32768 ; V dbuf 49152+v*16384 ;
// epilogue: T (64KB) aliases 0..65536, ml (2KB) at 65536 (inside V slot1).
#define LDS_VBASE 49152
#define LDS_ML 65536

__device__ __forceinline__ unsigned int pk2(float a, float b) {
  __half2 h = __float22half2_rn(make_float2(a, b));
  return __builtin_bit_cast(unsigned int, h);
}

__device__ __forceinline__ void st8(void* dst, const float v[8]) {
  u32x4 u;
  u[0] = pk2(v[0], v[1]);
  u[1] = pk2(v[2], v[3]);
  u[2] = pk2(v[4], v[5]);
  u[3] = pk2(v[6], v[7]);
  *(u32x4*)dst = u;
}

__device__ __forceinline__ void gld16(const void* g, void* l) {
  __builtin_amdgcn_global_load_lds(
      (const __attribute__((address_space(1))) unsigned int*)g,
      (__attribute__((address_space(3))) unsigned int*)l, 16, 0, 0);
}

// --------------------------- pre-pass: Q --------------------------------
// Q' = fp16(Q * (log2e/sqrt(128)) * p_q[row]); row-major [B*S][128]
__global__ __launch_bounds__(256) void prep_q_k(const float* __restrict__ Q,
                                                const float* __restrict__ pq,
                                                char* __restrict__ qh) {
  size_t i = ((size_t)blockIdx.x * 256 + threadIdx.x) * 8;
  const float g = pq[i >> 7] * 0.12751743343158394f;  // (1/sqrt(128))*log2(e)
  float4 a = *(const float4*)(Q + i);
  float4 b = *(const float4*)(Q + i + 4);
  float v[8] = {a.x * g, a.y * g, a.z * g, a.w * g,
                b.x * g, b.y * g, b.z * g, b.w * g};
  st8(qh + i * 2, v);
}

// --------------------------- pre-pass: K,V images ------------------------
// K image tile (64x128): byte(key,d) = key*256 + ((2d) ^ ((key&7)<<4))
// V image tile:          byte(key,d) = d*128 + ((2key) ^ ((d&7)<<4))
__global__ __launch_bounds__(256) void prep_kv(
    const float* __restrict__ K, const float* __restrict__ V,
    const float* __restrict__ pk, char* __restrict__ kimg,
    char* __restrict__ vimg) {
  __shared__ float vt[64 * 132];
  const int t = threadIdx.x;
  const int bid = blockIdx.x;
  const int bq = bid & 15;
  const int kt = bid >> 4;
  const size_t rowbase = (size_t)bq * S_LEN + kt * 64;

  // stage V tile (fp32) into padded LDS for the transpose
#pragma unroll
  for (int cc = 0; cc < 8; ++cc) {
    const int f = cc * 256 + t;
    const int row = f >> 5;
    const int col = (f & 31) * 4;
    *(float4*)(vt + row * 132 + col) = *(const float4*)(V + (rowbase + row) * DD + col);
  }

  // K image: pure global->global, fold p_k
  char* kdst = kimg + (size_t)(bq * NT + kt) * TILE_BYTES;
#pragma unroll
  for (int cc = 0; cc < 4; ++cc) {
    const int p0 = (cc * 256 + t) * 16;
    const int key = p0 >> 8;
    const int d0 = ((p0 & 255) ^ ((key & 7) << 4)) >> 1;
    const float g = pk[rowbase + key];
    const float* src = K + (rowbase + key) * DD + d0;
    float4 a = *(const float4*)(src);
    float4 b = *(const float4*)(src + 4);
    float v[8] = {a.x * g, a.y * g, a.z * g, a.w * g,
                  b.x * g, b.y * g, b.z * g, b.w * g};
    st8(kdst + p0, v);
  }

  __syncthreads();

  // V image from LDS transpose
  char* vdst = vimg + (size_t)(bq * NT + kt) * TILE_BYTES;
#pragma unroll
  for (int cc = 0; cc < 4; ++cc) {
    const int p0 = (cc * 256 + t) * 16;
    const int dcol = p0 >> 7;
    const int key0 = ((p0 & 127) ^ ((dcol & 7) << 4)) >> 1;
    float v[8];
#pragma unroll
    for (int j = 0; j < 8; ++j) v[j] = vt[(key0 + j) * 132 + dcol];
    st8(vdst + p0, v);
  }
}

// --------------------------- main attention ------------------------------
// 512 threads = 8 waves: wid = qs*2 + ks; qs in [0,4) picks a 32-q subtile,
// ks in {0,1} picks the key-half of each 64-key tile (independent online
// softmax per key-half; partials merged in the epilogue through LDS).
// 2-deep pipeline: QK(t+1) MFMAs issued before softmax(t) VALU + PV(t).
__global__ __launch_bounds__(512, 2) void attn_main(const char* __restrict__ qh,
                                                    const char* __restrict__ kimg,
                                                    const char* __restrict__ vimg,
                                                    float* __restrict__ out) {
  __shared__ float4 ldsraw[5120];  // 81920 B: K ring 48K + V dbuf 32K (+T/ml alias)
  char* lds = (char*)ldsraw;
  const int tid = threadIdx.x;
  const int wid = tid >> 6;
  const int qs = wid >> 1;   // q subtile 0..3
  const int ks = wid & 1;    // key half of tile 0..1
  const int lane = tid & 63;
  const int c = lane & 31;
  const int h = lane >> 5;
  const int swz = (c & 7) << 4;
  const int bid = blockIdx.x;
  const int bq = 2 * (bid & 7) + ((bid >> 3) & 1);  // batch pinned to XCD
  const int qt = bid >> 4;                          // q-tile (128 rows)
  const int q0 = qt * 128 + qs * 32;

  // Q fragments (B-operand of swapped QK^T): lane c = q row, 8 d's per kc
  f16x8 qf[8];
  const char* qrow = qh + (size_t)(bq * S_LEN + q0 + c) * (DD * 2);
#pragma unroll
  for (int kc = 0; kc < 8; ++kc) qf[kc] = *(const f16x8*)(qrow + kc * 32 + h * 16);

  f32x16 acc[4];
#pragma unroll
  for (int d = 0; d < 4; ++d) {
#pragma unroll
    for (int r = 0; r < 16; ++r) acc[d][r] = 0.f;
  }
  float m_run = -1.0e30f, l_run = 0.f;

  const char* kb = kimg + (size_t)bq * (NT * TILE_BYTES);
  const char* vb = vimg + (size_t)bq * (NT * TILE_BYTES);

  // prologue: stage K(0)->slot0, K(1)->slot1, V(0)->vslot0
#pragma unroll
  for (int j = 0; j < 2; ++j) {
    gld16(kb + j * 8192 + tid * 16, lds + j * 8192 + tid * 16);
    gld16(kb + TILE_BYTES + j * 8192 + tid * 16, lds + TILE_BYTES + j * 8192 + tid * 16);
    gld16(vb + j * 8192 + tid * 16, lds + LDS_VBASE + j * 8192 + tid * 16);
  }
  __syncthreads();

  // QK(0) from K slot 0
  const int krow_off = (ks * 32 + c) * 256;
  f32x16 sA;
#pragma unroll
  for (int r = 0; r < 16; ++r) sA[r] = 0.f;
  __builtin_amdgcn_s_setprio(1);
#pragma unroll
  for (int kc = 0; kc < 8; ++kc) {
    f16x8 kf = *(const f16x8*)(lds + krow_off + ((kc * 32 + h * 16) ^ swz));
    sA = __builtin_amdgcn_mfma_f32_32x32x16_f16(kf, qf[kc], sA, 0, 0, 0);
  }
  __builtin_amdgcn_s_setprio(0);

  int kwr = 2;  // K ring slot for tile t+2
  int krd = 1;  // K ring slot for tile t+1
#pragma unroll 2
  for (int kt = 0; kt < NT; ++kt) {
    __syncthreads();  // K(t+1), V(t) staged; slots (t+2)%3 / (t+1)&1 free

    // issue next stages (no wait; drained by next iter's barrier)
    if (kt + 2 < NT) {
      const char* kn = kb + (size_t)(kt + 2) * TILE_BYTES;
      char* kdst = lds + kwr * TILE_BYTES;
#pragma unroll
      for (int j = 0; j < 2; ++j)
        gld16(kn + j * 8192 + tid * 16, kdst + j * 8192 + tid * 16);
    }
    if (kt + 1 < NT) {
      const char* vn = vb + (size_t)(kt + 1) * TILE_BYTES;
      char* vdst = lds + LDS_VBASE + ((kt + 1) & 1) * TILE_BYTES;
#pragma unroll
      for (int j = 0; j < 2; ++j)
        gld16(vn + j * 8192 + tid * 16, vdst + j * 8192 + tid * 16);
    }

    // QK(t+1) -> sB (MFMA pipe; softmax(t) VALU below runs in its shadow)
    f32x16 sB;
#pragma unroll
    for (int r = 0; r < 16; ++r) sB[r] = 0.f;
    if (kt + 1 < NT) {
      const char* kl = lds + krd * TILE_BYTES;
      __builtin_amdgcn_s_setprio(1);
#pragma unroll
      for (int kc = 0; kc < 8; ++kc) {
        f16x8 kf = *(const f16x8*)(kl + krow_off + ((kc * 32 + h * 16) ^ swz));
        sB = __builtin_amdgcn_mfma_f32_32x32x16_f16(kf, qf[kc], sB, 0, 0, 0);
      }
      __builtin_amdgcn_s_setprio(0);
    }

    // lane-local online softmax of tile t (log2 domain; row q = c)
    float m0 = fmaxf(sA[0], sA[1]), m1 = fmaxf(sA[2], sA[3]);
    float m2 = fmaxf(sA[4], sA[5]), m3 = fmaxf(sA[6], sA[7]);
    float m4 = fmaxf(sA[8], sA[9]), m5 = fmaxf(sA[10], sA[11]);
    float m6 = fmaxf(sA[12], sA[13]), m7 = fmaxf(sA[14], sA[15]);
    m0 = fmaxf(m0, m1); m2 = fmaxf(m2, m3); m4 = fmaxf(m4, m5); m6 = fmaxf(m6, m7);
    float cm = fmaxf(fmaxf(m0, m2), fmaxf(m4, m6));
    cm = fmaxf(cm, __shfl_xor(cm, 32));
    if (__any(cm > m_run + 11.0f)) {  // defer-max: rescale only on real growth
      const float mn = fmaxf(m_run, cm);
      const float al = EXP2(m_run - mn);
      m_run = mn;
      l_run *= al;
#pragma unroll
      for (int d = 0; d < 4; ++d) {
#pragma unroll
        for (int r = 0; r < 16; ++r) acc[d][r] *= al;
      }
    }
    float ps0 = 0.f, ps1 = 0.f;
#pragma unroll
    for (int r = 0; r < 8; ++r) {
      sA[r] = EXP2(sA[r] - m_run);         ps0 += sA[r];
      sA[r + 8] = EXP2(sA[r + 8] - m_run); ps1 += sA[r + 8];
    }
    l_run += ps0 + ps1;

    // PV(t): O^T += V^T P^T over the wave's two local 16-key chunks
    const char* vl = lds + LDS_VBASE + (kt & 1) * TILE_BYTES;
#pragma unroll
    for (int kc = 0; kc < 2; ++kc) {
      const int A = kc * 8;
      const int Bb = A + 4;
      unsigned pA0 = pk2(sA[A + 0], sA[A + 1]);
      unsigned pA1 = pk2(sA[A + 2], sA[A + 3]);
      unsigned pB0 = pk2(sA[Bb + 0], sA[Bb + 1]);
      unsigned pB1 = pk2(sA[Bb + 2], sA[Bb + 3]);
      unsigned own0 = h ? pB0 : pA0;
      unsigned own1 = h ? pB1 : pA1;
      unsigned snd0 = h ? pA0 : pB0;
      unsigned snd1 = h ? pA1 : pB1;
      unsigned rcv0 = __shfl_xor(snd0, 32);
      unsigned rcv1 = __shfl_xor(snd1, 32);
      u32x4 pw;
      pw[0] = h ? rcv0 : own0;  // elems 0,1 (source half h=0)
      pw[1] = h ? rcv1 : own1;  // elems 2,3
      pw[2] = h ? own0 : rcv0;  // elems 4,5 (source half h=1)
      pw[3] = h ? own1 : rcv1;  // elems 6,7
      f16x8 pf = __builtin_bit_cast(f16x8, pw);
      const int kci = ks * 2 + kc;  // global 16-key chunk in tile
      __builtin_amdgcn_s_setprio(1);
#pragma unroll
      for (int d = 0; d < 4; ++d) {
        f16x8 vf = *(const f16x8*)(vl + (d * 32 + c) * 128 + ((kci * 32 + h * 16) ^ swz));
        acc[d] = __builtin_amdgcn_mfma_f32_32x32x16_f16(vf, pf, acc[d], 0, 0, 0);
      }
      __builtin_amdgcn_s_setprio(0);
    }

    sA = sB;                       // role swap (unroll 2 renames, no copies)
    krd = (krd == 2) ? 0 : krd + 1;
    kwr = (kwr == 2) ? 0 : kwr + 1;
  }

  // ---- epilogue: merge the two key-half partials, transpose, store ----
  l_run += __shfl_xor(l_run, 32);  // full half-range sum for row q=c

  __syncthreads();  // all waves done with stage buffers
  float2* ml = (float2*)(lds + LDS_ML);
  if (h == 0) ml[wid * 32 + c] = make_float2(m_run, l_run);
  __syncthreads();
  const float2 po = ml[(wid ^ 1) * 32 + c];  // partner key-half (same qs)
  const float ms = fmaxf(m_run, po.x);
  const float lstar = l_run * EXP2(m_run - ms) + po.y * EXP2(po.x - ms);
  const float w = EXP2(m_run - ms) / lstar;

  char* T = lds;  // 128 q x 128 d fp32 (64KB), swizzled rows
  if (ks == 0) {
#pragma unroll
    for (int d = 0; d < 4; ++d) {
#pragma unroll
      for (int rr = 0; rr < 4; ++rr) {
        const int dd = d * 32 + rr * 8 + h * 4;
        float4 v4;
        v4.x = acc[d][rr * 4 + 0] * w;
        v4.y = acc[d][rr * 4 + 1] * w;
        v4.z = acc[d][rr * 4 + 2] * w;
        v4.w = acc[d][rr * 4 + 3] * w;
        *(float4*)(T + (qs * 32 + c) * 512 + ((dd * 4) ^ swz)) = v4;
      }
    }
  }
  __syncthreads();
  if (ks == 1) {
#pragma unroll
    for (int d = 0; d < 4; ++d) {
#pragma unroll
      for (int rr = 0; rr < 4; ++rr) {
        const int dd = d * 32 + rr * 8 + h * 4;
        float4* p = (float4*)(T + (qs * 32 + c) * 512 + ((dd * 4) ^ swz));
        float4 t = *p;
        t.x += acc[d][rr * 4 + 0] * w;
        t.y += acc[d][rr * 4 + 1] * w;
        t.z += acc[d][rr * 4 + 2] * w;
        t.w += acc[d][rr * 4 + 3] * w;
        *p = t;
      }
    }
  }
  __syncthreads();

  float* obase = out + ((size_t)bq * S_LEN + qt * 128) * DD;
#pragma unroll
  for (int p = 0; p < 8; ++p) {
    const int idx = p * 512 + tid;
    const int q = idx >> 5;
    const int d0 = (idx & 31) * 4;
    float4 v4 = *(const float4*)(T + q * 512 + ((d0 * 4) ^ ((q & 7) << 4)));
    *(float4*)(obase + q * DD + d0) = v4;
  }
}

// --------------------------- launcher ------------------------------------
extern "C" void kernel_launch(void* const* d_in, const int* in_sizes, int n_in,
                              void* d_out, int out_size, void* d_ws, size_t ws_size,
                              hipStream_t stream) {
  const float* Q = (const float*)d_in[0];
  const float* K = (const float*)d_in[1];
  const float* V = (const float*)d_in[2];
  const float* pq = (const float*)d_in[3];
  const float* pk = (const float*)d_in[4];
  float* out = (float*)d_out;
  char* ws = (char*)d_ws;
  char* qh = ws;                         // 8 MB fp16 scaled Q (log2e folded)
  char* kimg = ws + (8u << 20);          // 8 MB K image (gated, swizzled)
  char* vimg = ws + (16u << 20);         // 8 MB V image (transposed, swizzled)

  prep_q_k<<<2048, 256, 0, stream>>>(Q, pq, qh);
  prep_kv<<<512, 256, 0, stream>>>(K, V, pk, kimg, vimg);
  attn_main<<<256, 512, 0, stream>>>(qh, kimg, vimg, out);
}